// Round 18
// baseline (57.552 us; speedup 1.0000x reference)
//
#include <hip/hip_runtime.h>
#include <math.h>

// Dims (fixed per reference)
#define B   128
#define L   50
#define V   100000
#define ND  4
#define D   64

// out layout: P_v (B*V) | infomax_loss (1) | gnn (B*ND*L*D)

typedef __attribute__((ext_vector_type(8))) short s8v;   // 8 bf16 (4 VGPR)
typedef __attribute__((ext_vector_type(4))) float f4v;   // MFMA acc

__device__ __forceinline__ float log_sigmoid(float x) {
    if (x >= 0.f) return -log1pf(expf(-x));
    return x - log1pf(expf(x));
}

// bf16 round-to-nearest-even helpers
__device__ __forceinline__ short bf16rne(float x) {
    unsigned u = __float_as_uint(x);
    unsigned r = u + 0x7FFFu + ((u >> 16) & 1u);
    return (short)(r >> 16);
}
__device__ __forceinline__ float bf16f(short s) {
    return __uint_as_float(((unsigned)(unsigned short)s) << 16);
}

// K0: gnn broadcast-write, full-GPU wide. One float4 per thread.
__global__ __launch_bounds__(256) void k0_gnn(
    const int* __restrict__ nodes, const float* __restrict__ emb_i,
    float* __restrict__ gnn)
{
    const int idx = blockIdx.x * 256 + threadIdx.x;   // float4 index
    const int d4   = idx & (D / 4 - 1);               // 0..15
    const int rest = idx >> 4;                        // b*ND*L + n*L + l
    const int l    = rest % L;
    const int bn   = rest / L;
    const int b    = bn >> 2;
    const int node = nodes[b * L + l];
    const float4 val = reinterpret_cast<const float4*>(emb_i)[node * (D / 4) + d4];
    reinterpret_cast<float4*>(gnn)[idx] = val;
}

// K1 (R17 post-mortem: the 64-thread serial 50-gather left latency fully
// exposed at 0.5 blocks/CU — restore the 256-thread parallel gather).
// 4 l-lanes per d + LDS reduction, then u/h on the first 64 threads.
// h written as bf16 hi/lo pair for the MFMA GEMM. Zero-inits loss.
__global__ __launch_bounds__(256) void k1_fused(
    const int* __restrict__ nodes, const int* __restrict__ mask,
    const int* __restrict__ sli, const float* __restrict__ emb_i,
    const float* __restrict__ W_pvsd, const float* __restrict__ b_pvsd,
    const float* __restrict__ W_im,
    float* __restrict__ u, short* __restrict__ hh, short* __restrict__ hl,
    float* __restrict__ loss)
{
    const int b = blockIdx.x;
    const int t = threadIdx.x;
    if (b == 0 && t == 0) loss[0] = 0.f;
    __shared__ int   s_nodes[L];
    __shared__ float s_mask[L];
    __shared__ float s_part[4][D];
    __shared__ float s_gr[D], s_last[D];
    if (t < L) {
        s_nodes[t] = nodes[b * L + t];
        s_mask[t]  = (float)mask[b * L + t];
    }
    __syncthreads();
    const int d  = t & 63;
    const int l0 = t >> 6;
    float acc = 0.f;
    for (int l = l0; l < L; l += 4)
        acc += s_mask[l] * emb_i[(size_t)s_nodes[l] * D + d];
    s_part[l0][d] = acc;
    __syncthreads();
    if (t < D) {
        float msum = 0.f;
        for (int l = 0; l < L; ++l) msum += s_mask[l];
        float s = s_part[0][t] + s_part[1][t] + s_part[2][t] + s_part[3][t];
        s_gr[t]   = s / msum;
        s_last[t] = emb_i[(size_t)s_nodes[sli[b]] * D + t];
    }
    __syncthreads();
    if (t < D) {
        float uu = 0.f;
        #pragma unroll
        for (int e = 0; e < D; ++e) uu += W_im[t * D + e] * s_gr[e];
        u[b * D + t] = uu;
        float pre = b_pvsd[t];
        #pragma unroll
        for (int k = 0; k < D; ++k) pre += s_gr[k]   * W_pvsd[k * D + t];
        #pragma unroll
        for (int k = 0; k < D; ++k) pre += s_last[k] * W_pvsd[(D + k) * D + t];
        float hv = tanhf(pre);
        short hi = bf16rne(hv);
        short lo = bf16rne(hv - bf16f(hi));
        hh[b * D + t] = hi;
        hl[b * D + t] = lo;
    }
}

// K3: infomax partials per b, accumulated into the scalar loss.
__global__ __launch_bounds__(64) void k3_infomax(
    const float* __restrict__ u, const float* __restrict__ gnn,
    float* __restrict__ loss)
{
    const int b = blockIdx.x;
    const int t = threadIdx.x;
    __shared__ float s_up[D], s_un[D];
    const int bm1 = (b + B - 1) % B;
    s_up[t] = u[b * D + t];
    s_un[t] = u[bm1 * D + t];
    __syncthreads();
    float lsp = 0.f, lsn = 0.f;
    if (t < L) {
        const float* se = gnn + ((size_t)(b * ND) * L + t) * D;  // n=0 copy
        float sp = 0.f, sn = 0.f;
        #pragma unroll
        for (int d2 = 0; d2 < D; ++d2) {
            float vv = se[d2];
            sp += vv * s_up[d2];
            sn += vv * s_un[d2];
        }
        lsp = log_sigmoid(sp);
        lsn = log_sigmoid(-sn);
    }
    float tot = lsp + lsn;
    for (int off = 32; off > 0; off >>= 1) tot += __shfl_down(tot, off);
    if (t == 0) atomicAdd(loss, -tot / (float)(B * L));
}

// K5: P_v = h(128x64) @ emb^T via bf16x3 MFMA.
// R17 worked (k5 51 -> <40us); remaining theory-backed costs:
//  (1) 8-deep serial MFMA chain per tile -> drop lo*lo (bf16x3, error
//      ~2e-7 << 3e-5 absmax) and split into TWO independent 3-chains
//      (depth 8 -> 3), final f4 add.
//  (2) L1 thrash: emb stream (4KB/wave) evicts the 32KB h-panel (exactly
//      L1-size). Non-temporal emb loads + pv stores keep L1 for h.
// Layout per HW-verified m89: A,B loaded [free=lane&15][k=8*(lane>>4)+i];
// C/D row=4*(lane>>4)+reg, col=lane&15 -> col=v -> coalesced 64B stores.
__global__ __launch_bounds__(256, 4) void k5_mfma(
    const short* __restrict__ hh, const short* __restrict__ hl,
    const float* __restrict__ emb_i, float* __restrict__ pv)
{
    const int lane = threadIdx.x & 63;
    const int wid  = threadIdx.x >> 6;
    const int lm   = lane & 15;
    const int lg   = lane >> 4;
    const int v0   = (blockIdx.x * 4 + wid) * 16;
    const int vcol = v0 + lm;
    const int vld  = vcol < V ? vcol : (V - 1);

    // emb row chunk: k = 8*lg + i (kk=0) and +32 (kk=1); non-temporal.
    const float* ep = emb_i + (size_t)vld * D + 8 * lg;
    f4v ea = __builtin_nontemporal_load((const f4v*)(ep));
    f4v eb = __builtin_nontemporal_load((const f4v*)(ep + 4));
    f4v ec = __builtin_nontemporal_load((const f4v*)(ep + 32));
    f4v ed = __builtin_nontemporal_load((const f4v*)(ep + 36));

    s8v ehi0, elo0, ehi1, elo1;
    #pragma unroll
    for (int i = 0; i < 4; ++i) {
        { float x = ea[i]; short h = bf16rne(x); ehi0[i]     = h; elo0[i]     = bf16rne(x - bf16f(h)); }
        { float x = eb[i]; short h = bf16rne(x); ehi0[i + 4] = h; elo0[i + 4] = bf16rne(x - bf16f(h)); }
        { float x = ec[i]; short h = bf16rne(x); ehi1[i]     = h; elo1[i]     = bf16rne(x - bf16f(h)); }
        { float x = ed[i]; short h = bf16rne(x); ehi1[i + 4] = h; elo1[i + 4] = bf16rne(x - bf16f(h)); }
    }

    #pragma unroll
    for (int bt = 0; bt < 8; ++bt) {
        const int b = 16 * bt + lm;                    // A free dim = lane&15
        const short* hb = hh + b * D + 8 * lg;
        const short* lb = hl + b * D + 8 * lg;
        s8v ah0 = *(const s8v*)(hb);                   // cached: keep h in L1
        s8v ah1 = *(const s8v*)(hb + 32);
        s8v al0 = *(const s8v*)(lb);
        s8v al1 = *(const s8v*)(lb + 32);
        // bf16x3: hi*hi + hi*lo + lo*hi, two independent 3-chains
        f4v c0 = {0.f, 0.f, 0.f, 0.f};
        f4v c1 = {0.f, 0.f, 0.f, 0.f};
        c0 = __builtin_amdgcn_mfma_f32_16x16x32_bf16(ah0, ehi0, c0, 0, 0, 0);
        c1 = __builtin_amdgcn_mfma_f32_16x16x32_bf16(ah1, ehi1, c1, 0, 0, 0);
        c0 = __builtin_amdgcn_mfma_f32_16x16x32_bf16(ah0, elo0, c0, 0, 0, 0);
        c1 = __builtin_amdgcn_mfma_f32_16x16x32_bf16(ah1, elo1, c1, 0, 0, 0);
        c0 = __builtin_amdgcn_mfma_f32_16x16x32_bf16(al0, ehi0, c0, 0, 0, 0);
        c1 = __builtin_amdgcn_mfma_f32_16x16x32_bf16(al1, ehi1, c1, 0, 0, 0);
        if (vcol < V) {
            const int br = 16 * bt + 4 * lg;           // C row = 4*lg + reg
            __builtin_nontemporal_store(c0[0] + c1[0], &pv[(size_t)(br + 0) * V + vcol]);
            __builtin_nontemporal_store(c0[1] + c1[1], &pv[(size_t)(br + 1) * V + vcol]);
            __builtin_nontemporal_store(c0[2] + c1[2], &pv[(size_t)(br + 2) * V + vcol]);
            __builtin_nontemporal_store(c0[3] + c1[3], &pv[(size_t)(br + 3) * V + vcol]);
        }
    }
}

extern "C" void kernel_launch(void* const* d_in, const int* in_sizes, int n_in,
                              void* d_out, int out_size, void* d_ws, size_t ws_size,
                              hipStream_t stream)
{
    const int*   nodes  = (const int*)d_in[0];
    const int*   sli    = (const int*)d_in[4];
    const int*   mask   = (const int*)d_in[6];
    const float* emb_i  = (const float*)d_in[7];
    const float* W_pvsd = (const float*)d_in[13];
    const float* b_pvsd = (const float*)d_in[14];
    const float* W_im   = (const float*)d_in[15];

    float* pv   = (float*)d_out;               // B*V
    float* loss = pv + (size_t)B * V;          // 1
    float* gnn  = loss + 1;                    // B*ND*L*D

    float* ws = (float*)d_ws;
    float* u  = ws;                            // B*D floats
    short* hh = (short*)(u + B * D);           // B*D bf16 hi
    short* hl = hh + B * D;                    // B*D bf16 lo

    k0_gnn<<<(B * ND * L * (D / 4)) / 256, 256, 0, stream>>>(nodes, emb_i, gnn);
    k1_fused<<<B, 256, 0, stream>>>(nodes, mask, sli, emb_i, W_pvsd, b_pvsd,
                                    W_im, u, hh, hl, loss);
    k3_infomax<<<B, 64, 0, stream>>>(u, gnn, loss);
    // V/16 = 6250 v-tiles, 4 per block (one per wave)
    k5_mfma<<<(V / 16 + 3) / 4, 256, 0, stream>>>(hh, hl, emb_i, pv);
}

// Round 19
// 40.885 us; speedup vs baseline: 1.4077x; 1.4077x over previous
//
#include <hip/hip_runtime.h>
#include <math.h>

// Dims (fixed per reference)
#define B   128
#define L   50
#define V   100000
#define ND  4
#define D   64

// out layout: P_v (B*V) | infomax_loss (1) | gnn (B*ND*L*D)

typedef __attribute__((ext_vector_type(8))) short s8v;   // 8 bf16 (4 VGPR)
typedef __attribute__((ext_vector_type(4))) float f4v;   // MFMA acc

__device__ __forceinline__ float log_sigmoid(float x) {
    if (x >= 0.f) return -log1pf(expf(-x));
    return x - log1pf(expf(x));
}

// bf16 round-to-nearest-even helpers
__device__ __forceinline__ short bf16rne(float x) {
    unsigned u = __float_as_uint(x);
    unsigned r = u + 0x7FFFu + ((u >> 16) & 1u);
    return (short)(r >> 16);
}
__device__ __forceinline__ float bf16f(short s) {
    return __uint_as_float(((unsigned)(unsigned short)s) << 16);
}

// K0: gnn broadcast-write, full-GPU wide. One float4 per thread.
__global__ __launch_bounds__(256) void k0_gnn(
    const int* __restrict__ nodes, const float* __restrict__ emb_i,
    float* __restrict__ gnn)
{
    const int idx = blockIdx.x * 256 + threadIdx.x;   // float4 index
    const int d4   = idx & (D / 4 - 1);               // 0..15
    const int rest = idx >> 4;                        // b*ND*L + n*L + l
    const int l    = rest % L;
    const int bn   = rest / L;
    const int b    = bn >> 2;
    const int node = nodes[b * L + l];
    const float4 val = reinterpret_cast<const float4*>(emb_i)[node * (D / 4) + d4];
    reinterpret_cast<float4*>(gnn)[idx] = val;
}

// K1: 256-thread parallel gather (4 l-lanes per d + LDS reduction), then
// u/h on the first 64 threads. h written as bf16 hi/lo. Zero-inits loss.
__global__ __launch_bounds__(256) void k1_fused(
    const int* __restrict__ nodes, const int* __restrict__ mask,
    const int* __restrict__ sli, const float* __restrict__ emb_i,
    const float* __restrict__ W_pvsd, const float* __restrict__ b_pvsd,
    const float* __restrict__ W_im,
    float* __restrict__ u, short* __restrict__ hh, short* __restrict__ hl,
    float* __restrict__ loss)
{
    const int b = blockIdx.x;
    const int t = threadIdx.x;
    if (b == 0 && t == 0) loss[0] = 0.f;
    __shared__ int   s_nodes[L];
    __shared__ float s_mask[L];
    __shared__ float s_part[4][D];
    __shared__ float s_gr[D], s_last[D];
    if (t < L) {
        s_nodes[t] = nodes[b * L + t];
        s_mask[t]  = (float)mask[b * L + t];
    }
    __syncthreads();
    const int d  = t & 63;
    const int l0 = t >> 6;
    float acc = 0.f;
    for (int l = l0; l < L; l += 4)
        acc += s_mask[l] * emb_i[(size_t)s_nodes[l] * D + d];
    s_part[l0][d] = acc;
    __syncthreads();
    if (t < D) {
        float msum = 0.f;
        for (int l = 0; l < L; ++l) msum += s_mask[l];
        float s = s_part[0][t] + s_part[1][t] + s_part[2][t] + s_part[3][t];
        s_gr[t]   = s / msum;
        s_last[t] = emb_i[(size_t)s_nodes[sli[b]] * D + t];
    }
    __syncthreads();
    if (t < D) {
        float uu = 0.f;
        #pragma unroll
        for (int e = 0; e < D; ++e) uu += W_im[t * D + e] * s_gr[e];
        u[b * D + t] = uu;
        float pre = b_pvsd[t];
        #pragma unroll
        for (int k = 0; k < D; ++k) pre += s_gr[k]   * W_pvsd[k * D + t];
        #pragma unroll
        for (int k = 0; k < D; ++k) pre += s_last[k] * W_pvsd[(D + k) * D + t];
        float hv = tanhf(pre);
        short hi = bf16rne(hv);
        short lo = bf16rne(hv - bf16f(hi));
        hh[b * D + t] = hi;
        hl[b * D + t] = lo;
    }
}

// K3: infomax partials per b, accumulated into the scalar loss.
__global__ __launch_bounds__(64) void k3_infomax(
    const float* __restrict__ u, const float* __restrict__ gnn,
    float* __restrict__ loss)
{
    const int b = blockIdx.x;
    const int t = threadIdx.x;
    __shared__ float s_up[D], s_un[D];
    const int bm1 = (b + B - 1) % B;
    s_up[t] = u[b * D + t];
    s_un[t] = u[bm1 * D + t];
    __syncthreads();
    float lsp = 0.f, lsn = 0.f;
    if (t < L) {
        const float* se = gnn + ((size_t)(b * ND) * L + t) * D;  // n=0 copy
        float sp = 0.f, sn = 0.f;
        #pragma unroll
        for (int d2 = 0; d2 < D; ++d2) {
            float vv = se[d2];
            sp += vv * s_up[d2];
            sn += vv * s_un[d2];
        }
        lsp = log_sigmoid(sp);
        lsn = log_sigmoid(-sn);
    }
    float tot = lsp + lsn;
    for (int off = 32; off > 0; off >>= 1) tot += __shfl_down(tot, off);
    if (t == 0) atomicAdd(loss, -tot / (float)(B * L));
}

// K5: P_v = h(128x64) @ emb^T via bf16x3 MFMA, h-panel staged in LDS.
// R18 post-mortem: all pipes idle (Mfma 4%, VALU 7%, HBM 24%) at 40.7us —
// the per-lane h reads (32KB/wave, per-lane b addresses) hit L2/L3 with
// cross-XCD misses (~500-900cy), 32 dependent times per wave. Fix: stage
// hh+hl (32KB) into LDS once per block (coalesced 8-quad/thread copy),
// operand reads become ds_read_b128. Rows are 256B -> naive reads would be
// 16-way bank-conflicted (G4); XOR-swizzle the quad index with row&7 ->
// 2 lanes/bank-group = free (m136). NT hints dropped (NT stores caused
// 65MB WRITE_SIZE write-amplification; L1-thrash motive moot with LDS).
__global__ __launch_bounds__(256) void k5_mfma(
    const short* __restrict__ hh, const short* __restrict__ hl,
    const float* __restrict__ emb_i, float* __restrict__ pv)
{
    // LDS: 128 rows x 256B. Row b = 16 quads (16B each): phys quad p:
    // p = (q&8) | ((q&7) ^ (b&7)), q<8 from hh, q>=8 from hl.
    __shared__ short slds[B * 128];   // 32KB

    const int t = threadIdx.x;
    #pragma unroll
    for (int k = 0; k < 8; ++k) {
        const int i   = k * 256 + t;          // quad index 0..2047
        const int row = i >> 4;
        const int q   = i & 15;
        const int p   = (q & 8) | ((q & 7) ^ (row & 7));
        const short* src = (q < 8 ? hh : hl) + row * D + (q & 7) * 8;
        *(s8v*)(&slds[row * 128 + p * 8]) = *(const s8v*)(src);
    }
    __syncthreads();

    const int lane = t & 63;
    const int wid  = t >> 6;
    const int lm   = lane & 15;
    const int lg   = lane >> 4;
    const int v0   = (blockIdx.x * 4 + wid) * 16;
    const int vcol = v0 + lm;
    const int vld  = vcol < V ? vcol : (V - 1);

    // emb row chunk: k = 8*lg + i (kk=0) and +32 (kk=1)
    const float* ep = emb_i + (size_t)vld * D + 8 * lg;
    f4v ea = *(const f4v*)(ep);
    f4v eb = *(const f4v*)(ep + 4);
    f4v ec = *(const f4v*)(ep + 32);
    f4v ed = *(const f4v*)(ep + 36);

    s8v ehi0, elo0, ehi1, elo1;
    #pragma unroll
    for (int i = 0; i < 4; ++i) {
        { float x = ea[i]; short h = bf16rne(x); ehi0[i]     = h; elo0[i]     = bf16rne(x - bf16f(h)); }
        { float x = eb[i]; short h = bf16rne(x); ehi0[i + 4] = h; elo0[i + 4] = bf16rne(x - bf16f(h)); }
        { float x = ec[i]; short h = bf16rne(x); ehi1[i]     = h; elo1[i]     = bf16rne(x - bf16f(h)); }
        { float x = ed[i]; short h = bf16rne(x); ehi1[i + 4] = h; elo1[i + 4] = bf16rne(x - bf16f(h)); }
    }

    #pragma unroll
    for (int bt = 0; bt < 8; ++bt) {
        const int row = 16 * bt + lm;                  // A free dim = lane&15
        const int s   = lm & 7;
        const short* base = &slds[row * 128];
        s8v ah0 = *(const s8v*)(base + (((lg    ) ^ s) * 8));
        s8v ah1 = *(const s8v*)(base + (((lg + 4) ^ s) * 8));
        s8v al0 = *(const s8v*)(base + 64 + (((lg    ) ^ s) * 8));
        s8v al1 = *(const s8v*)(base + 64 + (((lg + 4) ^ s) * 8));
        // bf16x3: hi*hi + hi*lo + lo*hi, two independent 3-chains
        f4v c0 = {0.f, 0.f, 0.f, 0.f};
        f4v c1 = {0.f, 0.f, 0.f, 0.f};
        c0 = __builtin_amdgcn_mfma_f32_16x16x32_bf16(ah0, ehi0, c0, 0, 0, 0);
        c1 = __builtin_amdgcn_mfma_f32_16x16x32_bf16(ah1, ehi1, c1, 0, 0, 0);
        c0 = __builtin_amdgcn_mfma_f32_16x16x32_bf16(ah0, elo0, c0, 0, 0, 0);
        c1 = __builtin_amdgcn_mfma_f32_16x16x32_bf16(ah1, elo1, c1, 0, 0, 0);
        c0 = __builtin_amdgcn_mfma_f32_16x16x32_bf16(al0, ehi0, c0, 0, 0, 0);
        c1 = __builtin_amdgcn_mfma_f32_16x16x32_bf16(al1, ehi1, c1, 0, 0, 0);
        if (vcol < V) {
            const int br = 16 * bt + 4 * lg;           // C row = 4*lg + reg
            pv[(size_t)(br + 0) * V + vcol] = c0[0] + c1[0];
            pv[(size_t)(br + 1) * V + vcol] = c0[1] + c1[1];
            pv[(size_t)(br + 2) * V + vcol] = c0[2] + c1[2];
            pv[(size_t)(br + 3) * V + vcol] = c0[3] + c1[3];
        }
    }
}

extern "C" void kernel_launch(void* const* d_in, const int* in_sizes, int n_in,
                              void* d_out, int out_size, void* d_ws, size_t ws_size,
                              hipStream_t stream)
{
    const int*   nodes  = (const int*)d_in[0];
    const int*   sli    = (const int*)d_in[4];
    const int*   mask   = (const int*)d_in[6];
    const float* emb_i  = (const float*)d_in[7];
    const float* W_pvsd = (const float*)d_in[13];
    const float* b_pvsd = (const float*)d_in[14];
    const float* W_im   = (const float*)d_in[15];

    float* pv   = (float*)d_out;               // B*V
    float* loss = pv + (size_t)B * V;          // 1
    float* gnn  = loss + 1;                    // B*ND*L*D

    float* ws = (float*)d_ws;
    float* u  = ws;                            // B*D floats
    short* hh = (short*)(u + B * D);           // B*D bf16 hi
    short* hl = hh + B * D;                    // B*D bf16 lo

    k0_gnn<<<(B * ND * L * (D / 4)) / 256, 256, 0, stream>>>(nodes, emb_i, gnn);
    k1_fused<<<B, 256, 0, stream>>>(nodes, mask, sli, emb_i, W_pvsd, b_pvsd,
                                    W_im, u, hh, hl, loss);
    k3_infomax<<<B, 64, 0, stream>>>(u, gnn, loss);
    // V/16 = 6250 v-tiles, 4 per block (one per wave)
    k5_mfma<<<(V / 16 + 3) / 4, 256, 0, stream>>>(hh, hl, emb_i, pv);
}

// Round 20
// 37.204 us; speedup vs baseline: 1.5469x; 1.0989x over previous
//
#include <hip/hip_runtime.h>
#include <math.h>

// Dims (fixed per reference)
#define B   128
#define L   50
#define V   100000
#define ND  4
#define D   64

// out layout: P_v (B*V) | infomax_loss (1) | gnn (B*ND*L*D)

typedef __attribute__((ext_vector_type(8))) short s8v;   // 8 bf16 (4 VGPR)
typedef __attribute__((ext_vector_type(4))) float f4v;   // MFMA acc

__device__ __forceinline__ float log_sigmoid(float x) {
    if (x >= 0.f) return -log1pf(expf(-x));
    return x - log1pf(expf(x));
}

// bf16 round-to-nearest-even helpers
__device__ __forceinline__ short bf16rne(float x) {
    unsigned u = __float_as_uint(x);
    unsigned r = u + 0x7FFFu + ((u >> 16) & 1u);
    return (short)(r >> 16);
}
__device__ __forceinline__ float bf16f(short s) {
    return __uint_as_float(((unsigned)(unsigned short)s) << 16);
}

// K1: gather + gnn broadcast-write (k0 merged back in — one fewer launch),
// masked-mean gr, last row, u = W_im@gr, h = tanh([gr|last]@W_pvsd + b)
// written as bf16 hi/lo. Zero-inits loss.
__global__ __launch_bounds__(256) void k1_fused(
    const int* __restrict__ nodes, const int* __restrict__ mask,
    const int* __restrict__ sli, const float* __restrict__ emb_i,
    const float* __restrict__ W_pvsd, const float* __restrict__ b_pvsd,
    const float* __restrict__ W_im,
    float* __restrict__ gnn_out, float* __restrict__ u,
    short* __restrict__ hh, short* __restrict__ hl,
    float* __restrict__ loss)
{
    const int b = blockIdx.x;
    const int t = threadIdx.x;
    if (b == 0 && t == 0) loss[0] = 0.f;
    __shared__ int   s_nodes[L];
    __shared__ float s_mask[L];
    __shared__ float s_part[4][D];
    __shared__ float s_gr[D], s_last[D];
    if (t < L) {
        s_nodes[t] = nodes[b * L + t];
        s_mask[t]  = (float)mask[b * L + t];
    }
    __syncthreads();
    const int d  = t & 63;
    const int l0 = t >> 6;
    float acc = 0.f;
    for (int l = l0; l < L; l += 4) {
        float val = emb_i[(size_t)s_nodes[l] * D + d];
        size_t o = ((size_t)(b * ND + 0) * L + l) * D + d;
        gnn_out[o]                   = val;
        gnn_out[o + (size_t)L * D]   = val;
        gnn_out[o + 2*(size_t)L * D] = val;
        gnn_out[o + 3*(size_t)L * D] = val;
        acc += s_mask[l] * val;
    }
    s_part[l0][d] = acc;
    __syncthreads();
    if (t < D) {
        float msum = 0.f;
        for (int l = 0; l < L; ++l) msum += s_mask[l];
        float s = s_part[0][t] + s_part[1][t] + s_part[2][t] + s_part[3][t];
        s_gr[t]   = s / msum;
        s_last[t] = emb_i[(size_t)s_nodes[sli[b]] * D + t];
    }
    __syncthreads();
    if (t < D) {
        float uu = 0.f;
        #pragma unroll
        for (int e = 0; e < D; ++e) uu += W_im[t * D + e] * s_gr[e];
        u[b * D + t] = uu;
        float pre = b_pvsd[t];
        #pragma unroll
        for (int k = 0; k < D; ++k) pre += s_gr[k]   * W_pvsd[k * D + t];
        #pragma unroll
        for (int k = 0; k < D; ++k) pre += s_last[k] * W_pvsd[(D + k) * D + t];
        float hv = tanhf(pre);
        short hi = bf16rne(hv);
        short lo = bf16rne(hv - bf16f(hi));
        hh[b * D + t] = hi;
        hl[b * D + t] = lo;
    }
}

// K3: infomax partials per b, accumulated into the scalar loss.
__global__ __launch_bounds__(64) void k3_infomax(
    const float* __restrict__ u, const float* __restrict__ gnn,
    float* __restrict__ loss)
{
    const int b = blockIdx.x;
    const int t = threadIdx.x;
    __shared__ float s_up[D], s_un[D];
    const int bm1 = (b + B - 1) % B;
    s_up[t] = u[b * D + t];
    s_un[t] = u[bm1 * D + t];
    __syncthreads();
    float lsp = 0.f, lsn = 0.f;
    if (t < L) {
        const float* se = gnn + ((size_t)(b * ND) * L + t) * D;  // n=0 copy
        float sp = 0.f, sn = 0.f;
        #pragma unroll
        for (int d2 = 0; d2 < D; ++d2) {
            float vv = se[d2];
            sp += vv * s_up[d2];
            sn += vv * s_un[d2];
        }
        lsp = log_sigmoid(sp);
        lsn = log_sigmoid(-sn);
    }
    float tot = lsp + lsn;
    for (int off = 32; off > 0; off >>= 1) tot += __shfl_down(tot, off);
    if (t == 0) atomicAdd(loss, -tot / (float)(B * L));
}

// K5: P_v = h(128x64) @ emb^T, bf16x3 MFMA, h in LDS (R19: -17us, theory
// confirmed). This round: VT=2 — each wave computes TWO 16-v tiles from
// one A-panel read stream: per bt the 4 ds_read_b128 now feed 12 MFMAs
// (was 6), 4 independent 3-chains (was 2), and the per-block 32KB stage
// is amortized over 2x output. launch_bounds(256,4): 128-VGPR budget for
// the 2nd B-operand set (avoids the 64-cap load-sink pathology, R4/R5).
__global__ __launch_bounds__(256, 4) void k5_mfma(
    const short* __restrict__ hh, const short* __restrict__ hl,
    const float* __restrict__ emb_i, float* __restrict__ pv)
{
    // LDS: 128 rows x 256B. Row b = 16 quads (16B): phys quad
    // p = (q&8) | ((q&7) ^ (b&7)); q<8 from hh, q>=8 from hl.
    __shared__ short slds[B * 128];   // 32KB

    const int t = threadIdx.x;
    #pragma unroll
    for (int k = 0; k < 8; ++k) {
        const int i   = k * 256 + t;          // quad index 0..2047
        const int row = i >> 4;
        const int q   = i & 15;
        const int p   = (q & 8) | ((q & 7) ^ (row & 7));
        const short* src = (q < 8 ? hh : hl) + row * D + (q & 7) * 8;
        *(s8v*)(&slds[row * 128 + p * 8]) = *(const s8v*)(src);
    }
    __syncthreads();

    const int lane = t & 63;
    const int wid  = t >> 6;
    const int lm   = lane & 15;
    const int lg   = lane >> 4;
    const int v0   = (blockIdx.x * 8 + wid * 2) * 16;   // two tiles: v0, v0+16
    const int vcA  = v0 + lm;
    const int vcB  = v0 + 16 + lm;
    const int vldA = vcA < V ? vcA : (V - 1);
    const int vldB = vcB < V ? vcB : (V - 1);

    // emb row chunks (k = 8*lg + i, and +32) for both v columns
    const float* epA = emb_i + (size_t)vldA * D + 8 * lg;
    const float* epB = emb_i + (size_t)vldB * D + 8 * lg;
    f4v ea0 = *(const f4v*)(epA),      ea1 = *(const f4v*)(epA + 4);
    f4v ea2 = *(const f4v*)(epA + 32), ea3 = *(const f4v*)(epA + 36);
    f4v eb0 = *(const f4v*)(epB),      eb1 = *(const f4v*)(epB + 4);
    f4v eb2 = *(const f4v*)(epB + 32), eb3 = *(const f4v*)(epB + 36);

    s8v Ahi0, Alo0, Ahi1, Alo1;   // B-operand for tile A
    s8v Bhi0, Blo0, Bhi1, Blo1;   // B-operand for tile B
    #pragma unroll
    for (int i = 0; i < 4; ++i) {
        { float x = ea0[i]; short h = bf16rne(x); Ahi0[i]   = h; Alo0[i]   = bf16rne(x - bf16f(h)); }
        { float x = ea1[i]; short h = bf16rne(x); Ahi0[i+4] = h; Alo0[i+4] = bf16rne(x - bf16f(h)); }
        { float x = ea2[i]; short h = bf16rne(x); Ahi1[i]   = h; Alo1[i]   = bf16rne(x - bf16f(h)); }
        { float x = ea3[i]; short h = bf16rne(x); Ahi1[i+4] = h; Alo1[i+4] = bf16rne(x - bf16f(h)); }
        { float x = eb0[i]; short h = bf16rne(x); Bhi0[i]   = h; Blo0[i]   = bf16rne(x - bf16f(h)); }
        { float x = eb1[i]; short h = bf16rne(x); Bhi0[i+4] = h; Blo0[i+4] = bf16rne(x - bf16f(h)); }
        { float x = eb2[i]; short h = bf16rne(x); Bhi1[i]   = h; Blo1[i]   = bf16rne(x - bf16f(h)); }
        { float x = eb3[i]; short h = bf16rne(x); Bhi1[i+4] = h; Blo1[i+4] = bf16rne(x - bf16f(h)); }
    }

    #pragma unroll
    for (int bt = 0; bt < 8; ++bt) {
        const int row = 16 * bt + lm;                  // A free dim = lane&15
        const int s   = lm & 7;
        const short* base = &slds[row * 128];
        s8v ah0 = *(const s8v*)(base + (((lg    ) ^ s) * 8));
        s8v ah1 = *(const s8v*)(base + (((lg + 4) ^ s) * 8));
        s8v al0 = *(const s8v*)(base + 64 + (((lg    ) ^ s) * 8));
        s8v al1 = *(const s8v*)(base + 64 + (((lg + 4) ^ s) * 8));
        // 4 independent 3-chains (bf16x3 per tile)
        f4v cA0 = {0.f,0.f,0.f,0.f}, cA1 = {0.f,0.f,0.f,0.f};
        f4v cB0 = {0.f,0.f,0.f,0.f}, cB1 = {0.f,0.f,0.f,0.f};
        cA0 = __builtin_amdgcn_mfma_f32_16x16x32_bf16(ah0, Ahi0, cA0, 0, 0, 0);
        cA1 = __builtin_amdgcn_mfma_f32_16x16x32_bf16(ah1, Ahi1, cA1, 0, 0, 0);
        cB0 = __builtin_amdgcn_mfma_f32_16x16x32_bf16(ah0, Bhi0, cB0, 0, 0, 0);
        cB1 = __builtin_amdgcn_mfma_f32_16x16x32_bf16(ah1, Bhi1, cB1, 0, 0, 0);
        cA0 = __builtin_amdgcn_mfma_f32_16x16x32_bf16(ah0, Alo0, cA0, 0, 0, 0);
        cA1 = __builtin_amdgcn_mfma_f32_16x16x32_bf16(ah1, Alo1, cA1, 0, 0, 0);
        cB0 = __builtin_amdgcn_mfma_f32_16x16x32_bf16(ah0, Blo0, cB0, 0, 0, 0);
        cB1 = __builtin_amdgcn_mfma_f32_16x16x32_bf16(ah1, Blo1, cB1, 0, 0, 0);
        cA0 = __builtin_amdgcn_mfma_f32_16x16x32_bf16(al0, Ahi0, cA0, 0, 0, 0);
        cA1 = __builtin_amdgcn_mfma_f32_16x16x32_bf16(al1, Ahi1, cA1, 0, 0, 0);
        cB0 = __builtin_amdgcn_mfma_f32_16x16x32_bf16(al0, Bhi0, cB0, 0, 0, 0);
        cB1 = __builtin_amdgcn_mfma_f32_16x16x32_bf16(al1, Bhi1, cB1, 0, 0, 0);
        const int br = 16 * bt + 4 * lg;               // C row = 4*lg + reg
        if (vcA < V) {
            pv[(size_t)(br + 0) * V + vcA] = cA0[0] + cA1[0];
            pv[(size_t)(br + 1) * V + vcA] = cA0[1] + cA1[1];
            pv[(size_t)(br + 2) * V + vcA] = cA0[2] + cA1[2];
            pv[(size_t)(br + 3) * V + vcA] = cA0[3] + cA1[3];
        }
        if (vcB < V) {
            pv[(size_t)(br + 0) * V + vcB] = cB0[0] + cB1[0];
            pv[(size_t)(br + 1) * V + vcB] = cB0[1] + cB1[1];
            pv[(size_t)(br + 2) * V + vcB] = cB0[2] + cB1[2];
            pv[(size_t)(br + 3) * V + vcB] = cB0[3] + cB1[3];
        }
    }
}

extern "C" void kernel_launch(void* const* d_in, const int* in_sizes, int n_in,
                              void* d_out, int out_size, void* d_ws, size_t ws_size,
                              hipStream_t stream)
{
    const int*   nodes  = (const int*)d_in[0];
    const int*   sli    = (const int*)d_in[4];
    const int*   mask   = (const int*)d_in[6];
    const float* emb_i  = (const float*)d_in[7];
    const float* W_pvsd = (const float*)d_in[13];
    const float* b_pvsd = (const float*)d_in[14];
    const float* W_im   = (const float*)d_in[15];

    float* pv   = (float*)d_out;               // B*V
    float* loss = pv + (size_t)B * V;          // 1
    float* gnn  = loss + 1;                    // B*ND*L*D

    float* ws = (float*)d_ws;
    float* u  = ws;                            // B*D floats
    short* hh = (short*)(u + B * D);           // B*D bf16 hi
    short* hl = hh + B * D;                    // B*D bf16 lo

    k1_fused<<<B, 256, 0, stream>>>(nodes, mask, sli, emb_i, W_pvsd, b_pvsd,
                                    W_im, gnn, u, hh, hl, loss);
    k3_infomax<<<B, 64, 0, stream>>>(u, gnn, loss);
    // each block: 8 16-v tiles (2 per wave) x all 128 b
    k5_mfma<<<(V + 127) / 128, 256, 0, stream>>>(hh, hl, emb_i, pv);
}

// Round 21
// 31.946 us; speedup vs baseline: 1.8016x; 1.1646x over previous
//
#include <hip/hip_runtime.h>
#include <math.h>

// Dims (fixed per reference)
#define B   128
#define L   50
#define V   100000
#define ND  4
#define D   64

// out layout: P_v (B*V) | infomax_loss (1) | gnn (B*ND*L*D)

typedef __attribute__((ext_vector_type(8))) short s8v;   // 8 bf16 (4 VGPR)
typedef __attribute__((ext_vector_type(4))) float f4v;   // MFMA acc

#define NVB ((V + 127) / 128)    // 782 v-blocks; blocks [NVB, NVB+B) do infomax

__device__ __forceinline__ float log_sigmoid(float x) {
    if (x >= 0.f) return -log1pf(expf(-x));
    return x - log1pf(expf(x));
}

// bf16 round-to-nearest-even helpers
__device__ __forceinline__ short bf16rne(float x) {
    unsigned u = __float_as_uint(x);
    unsigned r = u + 0x7FFFu + ((u >> 16) & 1u);
    return (short)(r >> 16);
}
__device__ __forceinline__ float bf16f(short s) {
    return __uint_as_float(((unsigned)(unsigned short)s) << 16);
}

// K1: gather + gnn broadcast-write, masked-mean gr, last row, u = W_im@gr,
// h = tanh([gr|last]@W_pvsd + b) written as bf16 hi/lo. Zero-inits loss.
__global__ __launch_bounds__(256) void k1_fused(
    const int* __restrict__ nodes, const int* __restrict__ mask,
    const int* __restrict__ sli, const float* __restrict__ emb_i,
    const float* __restrict__ W_pvsd, const float* __restrict__ b_pvsd,
    const float* __restrict__ W_im,
    float* __restrict__ gnn_out, float* __restrict__ u,
    short* __restrict__ hh, short* __restrict__ hl,
    float* __restrict__ loss)
{
    const int b = blockIdx.x;
    const int t = threadIdx.x;
    if (b == 0 && t == 0) loss[0] = 0.f;
    __shared__ int   s_nodes[L];
    __shared__ float s_mask[L];
    __shared__ float s_part[4][D];
    __shared__ float s_gr[D], s_last[D];
    if (t < L) {
        s_nodes[t] = nodes[b * L + t];
        s_mask[t]  = (float)mask[b * L + t];
    }
    __syncthreads();
    const int d  = t & 63;
    const int l0 = t >> 6;
    float acc = 0.f;
    for (int l = l0; l < L; l += 4) {
        float val = emb_i[(size_t)s_nodes[l] * D + d];
        size_t o = ((size_t)(b * ND + 0) * L + l) * D + d;
        gnn_out[o]                   = val;
        gnn_out[o + (size_t)L * D]   = val;
        gnn_out[o + 2*(size_t)L * D] = val;
        gnn_out[o + 3*(size_t)L * D] = val;
        acc += s_mask[l] * val;
    }
    s_part[l0][d] = acc;
    __syncthreads();
    if (t < D) {
        float msum = 0.f;
        for (int l = 0; l < L; ++l) msum += s_mask[l];
        float s = s_part[0][t] + s_part[1][t] + s_part[2][t] + s_part[3][t];
        s_gr[t]   = s / msum;
        s_last[t] = emb_i[(size_t)s_nodes[sli[b]] * D + t];
    }
    __syncthreads();
    if (t < D) {
        float uu = 0.f;
        #pragma unroll
        for (int e = 0; e < D; ++e) uu += W_im[t * D + e] * s_gr[e];
        u[b * D + t] = uu;
        float pre = b_pvsd[t];
        #pragma unroll
        for (int k = 0; k < D; ++k) pre += s_gr[k]   * W_pvsd[k * D + t];
        #pragma unroll
        for (int k = 0; k < D; ++k) pre += s_last[k] * W_pvsd[(D + k) * D + t];
        float hv = tanhf(pre);
        short hi = bf16rne(hv);
        short lo = bf16rne(hv - bf16f(hi));
        hh[b * D + t] = hi;
        hl[b * D + t] = lo;
    }
}

// K5m: blocks [0, NVB): P_v = h @ emb^T (bf16x3 MFMA, h-panel in LDS,
// VT=2 — unchanged from R20, which measured ~20us). Blocks [NVB, NVB+B):
// the infomax partials (former k3), running CONCURRENTLY with the
// v-blocks instead of as a serialized 0.5-block/CU dispatch between k1
// and k5 (R20 post-mortem: ~11us of 3-launch pipeline overhead vs a
// 25-26us component sum — the launch structure is now the target).
__global__ __launch_bounds__(256, 4) void k5_mfma(
    const short* __restrict__ hh, const short* __restrict__ hl,
    const float* __restrict__ emb_i, const float* __restrict__ u,
    const float* __restrict__ gnn, float* __restrict__ pv,
    float* __restrict__ loss)
{
    __shared__ short slds[B * 128];   // 32KB

    const int t = threadIdx.x;

    if (blockIdx.x >= NVB) {
        // ---- infomax branch (former k3), first 64 threads ----
        const int b = blockIdx.x - NVB;
        float* s_up = reinterpret_cast<float*>(slds);        // [D]
        float* s_un = s_up + D;                              // [D]
        if (t < D) {
            const int bm1 = (b + B - 1) % B;
            s_up[t] = u[b * D + t];
            s_un[t] = u[bm1 * D + t];
        }
        __syncthreads();
        if (t < 64) {
            float lsp = 0.f, lsn = 0.f;
            if (t < L) {
                const float* se = gnn + ((size_t)(b * ND) * L + t) * D;  // n=0
                float sp = 0.f, sn = 0.f;
                #pragma unroll
                for (int d2 = 0; d2 < D; ++d2) {
                    float vv = se[d2];
                    sp += vv * s_up[d2];
                    sn += vv * s_un[d2];
                }
                lsp = log_sigmoid(sp);
                lsn = log_sigmoid(-sn);
            }
            float tot = lsp + lsn;
            for (int off = 32; off > 0; off >>= 1) tot += __shfl_down(tot, off);
            if (t == 0) atomicAdd(loss, -tot / (float)(B * L));
        }
        return;
    }

    // ---- P_v branch (identical to R20) ----
    #pragma unroll
    for (int k = 0; k < 8; ++k) {
        const int i   = k * 256 + t;          // quad index 0..2047
        const int row = i >> 4;
        const int q   = i & 15;
        const int p   = (q & 8) | ((q & 7) ^ (row & 7));
        const short* src = (q < 8 ? hh : hl) + row * D + (q & 7) * 8;
        *(s8v*)(&slds[row * 128 + p * 8]) = *(const s8v*)(src);
    }
    __syncthreads();

    const int lane = t & 63;
    const int wid  = t >> 6;
    const int lm   = lane & 15;
    const int lg   = lane >> 4;
    const int v0   = (blockIdx.x * 8 + wid * 2) * 16;   // two tiles: v0, v0+16
    const int vcA  = v0 + lm;
    const int vcB  = v0 + 16 + lm;
    const int vldA = vcA < V ? vcA : (V - 1);
    const int vldB = vcB < V ? vcB : (V - 1);

    const float* epA = emb_i + (size_t)vldA * D + 8 * lg;
    const float* epB = emb_i + (size_t)vldB * D + 8 * lg;
    f4v ea0 = *(const f4v*)(epA),      ea1 = *(const f4v*)(epA + 4);
    f4v ea2 = *(const f4v*)(epA + 32), ea3 = *(const f4v*)(epA + 36);
    f4v eb0 = *(const f4v*)(epB),      eb1 = *(const f4v*)(epB + 4);
    f4v eb2 = *(const f4v*)(epB + 32), eb3 = *(const f4v*)(epB + 36);

    s8v Ahi0, Alo0, Ahi1, Alo1;
    s8v Bhi0, Blo0, Bhi1, Blo1;
    #pragma unroll
    for (int i = 0; i < 4; ++i) {
        { float x = ea0[i]; short h = bf16rne(x); Ahi0[i]   = h; Alo0[i]   = bf16rne(x - bf16f(h)); }
        { float x = ea1[i]; short h = bf16rne(x); Ahi0[i+4] = h; Alo0[i+4] = bf16rne(x - bf16f(h)); }
        { float x = ea2[i]; short h = bf16rne(x); Ahi1[i]   = h; Alo1[i]   = bf16rne(x - bf16f(h)); }
        { float x = ea3[i]; short h = bf16rne(x); Ahi1[i+4] = h; Alo1[i+4] = bf16rne(x - bf16f(h)); }
        { float x = eb0[i]; short h = bf16rne(x); Bhi0[i]   = h; Blo0[i]   = bf16rne(x - bf16f(h)); }
        { float x = eb1[i]; short h = bf16rne(x); Bhi0[i+4] = h; Blo0[i+4] = bf16rne(x - bf16f(h)); }
        { float x = eb2[i]; short h = bf16rne(x); Bhi1[i]   = h; Blo1[i]   = bf16rne(x - bf16f(h)); }
        { float x = eb3[i]; short h = bf16rne(x); Bhi1[i+4] = h; Blo1[i+4] = bf16rne(x - bf16f(h)); }
    }

    #pragma unroll
    for (int bt = 0; bt < 8; ++bt) {
        const int row = 16 * bt + lm;
        const int s   = lm & 7;
        const short* base = &slds[row * 128];
        s8v ah0 = *(const s8v*)(base + (((lg    ) ^ s) * 8));
        s8v ah1 = *(const s8v*)(base + (((lg + 4) ^ s) * 8));
        s8v al0 = *(const s8v*)(base + 64 + (((lg    ) ^ s) * 8));
        s8v al1 = *(const s8v*)(base + 64 + (((lg + 4) ^ s) * 8));
        f4v cA0 = {0.f,0.f,0.f,0.f}, cA1 = {0.f,0.f,0.f,0.f};
        f4v cB0 = {0.f,0.f,0.f,0.f}, cB1 = {0.f,0.f,0.f,0.f};
        cA0 = __builtin_amdgcn_mfma_f32_16x16x32_bf16(ah0, Ahi0, cA0, 0, 0, 0);
        cA1 = __builtin_amdgcn_mfma_f32_16x16x32_bf16(ah1, Ahi1, cA1, 0, 0, 0);
        cB0 = __builtin_amdgcn_mfma_f32_16x16x32_bf16(ah0, Bhi0, cB0, 0, 0, 0);
        cB1 = __builtin_amdgcn_mfma_f32_16x16x32_bf16(ah1, Bhi1, cB1, 0, 0, 0);
        cA0 = __builtin_amdgcn_mfma_f32_16x16x32_bf16(ah0, Alo0, cA0, 0, 0, 0);
        cA1 = __builtin_amdgcn_mfma_f32_16x16x32_bf16(ah1, Alo1, cA1, 0, 0, 0);
        cB0 = __builtin_amdgcn_mfma_f32_16x16x32_bf16(ah0, Blo0, cB0, 0, 0, 0);
        cB1 = __builtin_amdgcn_mfma_f32_16x16x32_bf16(ah1, Blo1, cB1, 0, 0, 0);
        cA0 = __builtin_amdgcn_mfma_f32_16x16x32_bf16(al0, Ahi0, cA0, 0, 0, 0);
        cA1 = __builtin_amdgcn_mfma_f32_16x16x32_bf16(al1, Ahi1, cA1, 0, 0, 0);
        cB0 = __builtin_amdgcn_mfma_f32_16x16x32_bf16(al0, Bhi0, cB0, 0, 0, 0);
        cB1 = __builtin_amdgcn_mfma_f32_16x16x32_bf16(al1, Bhi1, cB1, 0, 0, 0);
        const int br = 16 * bt + 4 * lg;
        if (vcA < V) {
            pv[(size_t)(br + 0) * V + vcA] = cA0[0] + cA1[0];
            pv[(size_t)(br + 1) * V + vcA] = cA0[1] + cA1[1];
            pv[(size_t)(br + 2) * V + vcA] = cA0[2] + cA1[2];
            pv[(size_t)(br + 3) * V + vcA] = cA0[3] + cA1[3];
        }
        if (vcB < V) {
            pv[(size_t)(br + 0) * V + vcB] = cB0[0] + cB1[0];
            pv[(size_t)(br + 1) * V + vcB] = cB0[1] + cB1[1];
            pv[(size_t)(br + 2) * V + vcB] = cB0[2] + cB1[2];
            pv[(size_t)(br + 3) * V + vcB] = cB0[3] + cB1[3];
        }
    }
}

extern "C" void kernel_launch(void* const* d_in, const int* in_sizes, int n_in,
                              void* d_out, int out_size, void* d_ws, size_t ws_size,
                              hipStream_t stream)
{
    const int*   nodes  = (const int*)d_in[0];
    const int*   sli    = (const int*)d_in[4];
    const int*   mask   = (const int*)d_in[6];
    const float* emb_i  = (const float*)d_in[7];
    const float* W_pvsd = (const float*)d_in[13];
    const float* b_pvsd = (const float*)d_in[14];
    const float* W_im   = (const float*)d_in[15];

    float* pv   = (float*)d_out;               // B*V
    float* loss = pv + (size_t)B * V;          // 1
    float* gnn  = loss + 1;                    // B*ND*L*D

    float* ws = (float*)d_ws;
    float* u  = ws;                            // B*D floats
    short* hh = (short*)(u + B * D);           // B*D bf16 hi
    short* hl = hh + B * D;                    // B*D bf16 lo

    k1_fused<<<B, 256, 0, stream>>>(nodes, mask, sli, emb_i, W_pvsd, b_pvsd,
                                    W_im, gnn, u, hh, hl, loss);
    // v-blocks + infomax blocks in one dispatch
    k5_mfma<<<NVB + B, 256, 0, stream>>>(hh, hl, emb_i, u, gnn, pv, loss);
}